// Round 1
// baseline (2628.022 us; speedup 1.0000x reference)
//
#include <hip/hip_runtime.h>

#define QINF 1000000000.0f
constexpr int B = 64;
constexpr int V = 8192;
constexpr int VP2 = V + 2;
constexpr int TI = 16;                    // i-rows per block
constexpr int STRIPS = 8;                 // j strips (grid.y)
constexpr int JSTRIP = V / STRIPS;        // 1024 j per block
constexpr int TJPANEL = 128;              // j per panel (4 waves x 32)
constexpr int PANELS = JSTRIP / TJPANEL;  // 8
constexpr int TJW = 32;                   // j per wave per panel

__global__ __launch_bounds__(64) void mask_kernel(const float* __restrict__ func,
                                                  float* __restrict__ out) {
    int b = threadIdx.x;
    if (b < B) {
        float f1 = func[(size_t)b * VP2 + V];
        float f2 = func[(size_t)b * VP2 + V + 1];
        out[b * 3 + 0] = -QINF * f1;
        out[b * 3 + 1] = -QINF * (1.0f - (1.0f - f1) * (1.0f - f2));
        out[b * 3 + 2] = 0.0f;
    }
}

__global__ __launch_bounds__(256) void cooc_kernel(const float* __restrict__ func,
                                                   const float* __restrict__ arg,
                                                   const float* __restrict__ cooc,
                                                   float* __restrict__ out) {
    // aT: [TJPANEL][65] (pad 65 breaks bank conflicts), fT: [TI][64]
    __shared__ float smem[TJPANEL * 65 + TI * 64];
    float* aT = smem;
    float* fT = smem + TJPANEL * 65;

    const int tid  = threadIdx.x;
    const int lane = tid & 63;  // lane == b
    const int g    = __builtin_amdgcn_readfirstlane(tid >> 6);  // wave id, uniform
    const int i0      = blockIdx.x * TI;
    const int jstrip0 = blockIdx.y * JSTRIP;

    // stage fT[ti][b] = func[b, i0+ti]  (tiny, L2-cached after first blocks)
    for (int idx = tid; idx < TI * 64; idx += 256) {
        int ti = idx >> 6, b = idx & 63;
        fT[idx] = func[(size_t)b * VP2 + i0 + ti];
    }

    float acc0 = 0.f, acc1 = 0.f, acc2 = 0.f;

    for (int p = 0; p < PANELS; ++p) {
        const int j0p = jstrip0 + p * TJPANEL;
        __syncthreads();  // protect aT from previous panel's readers
        // stage aT[j][b] = arg[b, j0p+j]; float2 (rows are only 8B-aligned: 8194*4%16!=0)
        #pragma unroll
        for (int it = 0; it < (TJPANEL * B / 2) / 256; ++it) {  // 16 iters
            int f2idx = tid + it * 256;
            int b  = f2idx >> 6;   // 64 float2 per 128-j row
            int j2 = f2idx & 63;
            const float2 v = *(const float2*)(arg + (size_t)b * VP2 + j0p + j2 * 2);
            aT[(j2 * 2 + 0) * 65 + b] = v.x;
            aT[(j2 * 2 + 1) * 65 + b] = v.y;
        }
        __syncthreads();

        // my 32 arg values into registers
        float areg[TJW];
        #pragma unroll
        for (int jj = 0; jj < TJW; ++jj)
            areg[jj] = aT[(g * TJW + jj) * 65 + lane];

        const int jbase = j0p + g * TJW;
        for (int ti = 0; ti < TI; ++ti) {
            // wave-uniform address: 64 lanes broadcast-read the same cooc stream
            const float4* cb = (const float4*)(cooc + ((size_t)(i0 + ti) * V + jbase) * 3);
            float t0 = 0.f, t1 = 0.f, t2 = 0.f;
            #pragma unroll
            for (int it = 0; it < TJW / 4; ++it) {
                // 12 floats = 4 j's worth of (k0,k1,k2) triples
                float4 x = cb[it * 3 + 0];
                float4 y = cb[it * 3 + 1];
                float4 z = cb[it * 3 + 2];
                float a0 = areg[it * 4 + 0], a1 = areg[it * 4 + 1];
                float a2 = areg[it * 4 + 2], a3 = areg[it * 4 + 3];
                t0 += a0 * x.x; t1 += a0 * x.y; t2 += a0 * x.z;
                t0 += a1 * x.w; t1 += a1 * y.x; t2 += a1 * y.y;
                t0 += a2 * y.z; t1 += a2 * y.w; t2 += a2 * z.x;
                t0 += a3 * z.y; t1 += a3 * z.z; t2 += a3 * z.w;
            }
            float f = fT[ti * 64 + lane];
            acc0 += f * t0; acc1 += f * t1; acc2 += f * t2;
        }
    }

    // cross-wave reduction, then one atomic per (b,k)
    __syncthreads();
    float* red = smem;  // reuse aT region (768 floats needed; fT untouched)
    red[g * 192 + lane * 3 + 0] = acc0;
    red[g * 192 + lane * 3 + 1] = acc1;
    red[g * 192 + lane * 3 + 2] = acc2;
    __syncthreads();
    if (tid < 192) {
        float s = red[tid] + red[192 + tid] + red[384 + tid] + red[576 + tid];
        atomicAdd(&out[tid], s);
    }
}

extern "C" void kernel_launch(void* const* d_in, const int* in_sizes, int n_in,
                              void* d_out, int out_size, void* d_ws, size_t ws_size,
                              hipStream_t stream) {
    const float* func = (const float*)d_in[0];
    const float* arg  = (const float*)d_in[1];
    const float* cooc = (const float*)d_in[2];
    float* out = (float*)d_out;

    // d_out is re-poisoned before every launch: write masks first, then accumulate.
    hipLaunchKernelGGL(mask_kernel, dim3(1), dim3(64), 0, stream, func, out);
    hipLaunchKernelGGL(cooc_kernel, dim3(V / TI, STRIPS), dim3(256), 0, stream,
                       func, arg, cooc, out);
}

// Round 2
// 1605.554 us; speedup vs baseline: 1.6368x; 1.6368x over previous
//
#include <hip/hip_runtime.h>

#define QINF 1000000000.0f
constexpr int B = 64;
constexpr int V = 8192;
constexpr int VP2 = V + 2;
constexpr int TI = 32;               // i per block (2 MFMA n-subtiles)
constexpr int NSJ = 8;               // j strips (grid.y)
constexpr int KSTRIP = V / NSJ;      // 1024 j per block
constexpr int JC = 128;              // j per staged chunk
constexpr int NCHUNK = KSTRIP / JC;  // 8
constexpr int ROWJ = JC + 8;         // padded LDS row (bf16): 272 B = 16*17 -> b128-aligned, 2-way banks (free)

using bf16x8 = __attribute__((ext_vector_type(8))) short;
using f32x4  = __attribute__((ext_vector_type(4))) float;

__device__ inline unsigned f2bf2(float a, float b) {
    // RNE float->bf16, packed pair (inputs are finite; no NaN handling needed)
    unsigned ua = __builtin_bit_cast(unsigned, a);
    unsigned ub = __builtin_bit_cast(unsigned, b);
    ua += 0x7FFFu + ((ua >> 16) & 1u);
    ub += 0x7FFFu + ((ub >> 16) & 1u);
    return (ua >> 16) | (ub & 0xFFFF0000u);
}

__global__ __launch_bounds__(64) void mask_kernel(const float* __restrict__ func,
                                                  float* __restrict__ out) {
    int b = threadIdx.x;
    if (b < B) {
        float f1 = func[(size_t)b * VP2 + V];
        float f2 = func[(size_t)b * VP2 + V + 1];
        out[b * 3 + 0] = -QINF * f1;
        out[b * 3 + 1] = -QINF * (1.0f - (1.0f - f1) * (1.0f - f2));
        out[b * 3 + 2] = 0.0f;
    }
}

__global__ __launch_bounds__(256) void cooc_kernel(const float* __restrict__ func,
                                                   const float* __restrict__ arg,
                                                   const float* __restrict__ cooc,
                                                   float* __restrict__ out) {
    __shared__ alignas(16) unsigned short at[B * ROWJ];       // arg bf16 [b][j]
    __shared__ alignas(16) unsigned short ck[3 * TI * ROWJ];  // cooc bf16 [kk][i][j]

    const int tid  = threadIdx.x;
    const int lane = tid & 63;
    const int w    = tid >> 6;      // wave 0..3 -> b rows 16w..16w+15
    const int il   = lane & 15;
    const int quad = lane >> 4;
    const int i0   = blockIdx.x * TI;
    const int j00  = blockIdx.y * KSTRIP;

    f32x4 acc[2][3] = {};  // [i-subtile][kk]

    for (int c = 0; c < NCHUNK; ++c) {
        const int j0 = j00 + c * JC;
        __syncthreads();  // protect LDS from previous chunk's readers

        // ---- stage cooc chunk: TI x JC x 3 floats; thread unit = 12 consecutive
        // floats = 4 j x 3 kk for one i. Register-transpose -> 3 x ds_write_b64.
        {
            int u = tid;
            #pragma unroll
            for (int it = 0; it < (TI * (JC / 4)) / 256; ++it, u += 256) {  // 4 iters
                const int iL = u >> 5;          // 0..31
                const int jL = (u & 31) * 4;    // 0,4,..,124
                const float4* gp = (const float4*)(cooc + ((size_t)(i0 + iL) * V + (j0 + jL)) * 3);
                float4 x = gp[0], y = gp[1], z = gp[2];
                const float fl[12] = {x.x, x.y, x.z, x.w, y.x, y.y, y.z, y.w, z.x, z.y, z.z, z.w};
                #pragma unroll
                for (int kk = 0; kk < 3; ++kk) {
                    uint2 pack;
                    pack.x = f2bf2(fl[0 * 3 + kk], fl[1 * 3 + kk]);
                    pack.y = f2bf2(fl[2 * 3 + kk], fl[3 * 3 + kk]);
                    *(uint2*)&ck[(kk * TI + iL) * ROWJ + jL] = pack;
                }
            }
        }
        // ---- stage arg chunk: 64 b x JC floats as bf16 pairs
        {
            const int b  = tid >> 2;   // 4 threads per row
            const int co = tid & 3;
            #pragma unroll
            for (int it = 0; it < 16; ++it) {
                const int c2 = co + it * 4;  // float2 index 0..63
                const float2 v = *(const float2*)(arg + (size_t)b * VP2 + j0 + c2 * 2);
                *(unsigned*)&at[b * ROWJ + c2 * 2] = f2bf2(v.x, v.y);
            }
        }
        __syncthreads();

        // ---- MFMA: D[b16][i16] += A[b16][j32] * B[j32][i16], 3 kk accs, 2 i-subtiles
        #pragma unroll
        for (int s = 0; s < JC / 32; ++s) {
            bf16x8 afrag = *(const bf16x8*)&at[(w * 16 + il) * ROWJ + s * 32 + quad * 8];
            #pragma unroll
            for (int t2 = 0; t2 < 2; ++t2) {
                #pragma unroll
                for (int kk = 0; kk < 3; ++kk) {
                    bf16x8 bfrag = *(const bf16x8*)&ck[(kk * TI + t2 * 16 + il) * ROWJ + s * 32 + quad * 8];
                    acc[t2][kk] = __builtin_amdgcn_mfma_f32_16x16x32_bf16(afrag, bfrag, acc[t2][kk], 0, 0, 0);
                }
            }
        }
    }

    // ---- epilogue: out[b,kk] += sum_i f[b,i] * P[b,i,kk]
    // C/D layout: col(=i_local) = lane&15, row(=b_local) = quad*4 + reg
    const int b0w = w * 16;
    float fv[2][4];
    #pragma unroll
    for (int t2 = 0; t2 < 2; ++t2)
        #pragma unroll
        for (int r = 0; r < 4; ++r)
            fv[t2][r] = func[(size_t)(b0w + quad * 4 + r) * VP2 + i0 + t2 * 16 + il];

    #pragma unroll
    for (int kk = 0; kk < 3; ++kk) {
        #pragma unroll
        for (int r = 0; r < 4; ++r) {
            float v = fv[0][r] * acc[0][kk][r] + fv[1][r] * acc[1][kk][r];
            v += __shfl_xor(v, 1);
            v += __shfl_xor(v, 2);
            v += __shfl_xor(v, 4);
            v += __shfl_xor(v, 8);
            if (il == 0) atomicAdd(&out[(b0w + quad * 4 + r) * 3 + kk], v);
        }
    }
}

extern "C" void kernel_launch(void* const* d_in, const int* in_sizes, int n_in,
                              void* d_out, int out_size, void* d_ws, size_t ws_size,
                              hipStream_t stream) {
    const float* func = (const float*)d_in[0];
    const float* arg  = (const float*)d_in[1];
    const float* cooc = (const float*)d_in[2];
    float* out = (float*)d_out;

    // d_out is re-poisoned before every launch: write masks first, then accumulate.
    hipLaunchKernelGGL(mask_kernel, dim3(1), dim3(64), 0, stream, func, out);
    hipLaunchKernelGGL(cooc_kernel, dim3(V / TI, NSJ), dim3(256), 0, stream,
                       func, arg, cooc, out);
}